// Round 7
// baseline (318.796 us; speedup 1.0000x reference)
//
#include <hip/hip_runtime.h>
#include <hip/hip_bf16.h>
#include <math.h>

typedef unsigned int   u32;
typedef unsigned short u16;
typedef __bf16 bf16;
typedef bf16  bf16x8  __attribute__((ext_vector_type(8)));
typedef float f32x4   __attribute__((ext_vector_type(4)));
typedef float f32x16  __attribute__((ext_vector_type(16)));

#define BBATCH 16
#define MTOK   16
#define NEXP   16
#define DDIM   512
#define HDIM   682
#define HPAD   704            // 11*64
#define NHCOL  (NEXP*HDIM)    // 10912
#define NHPCOL (NEXP*HPAD)    // 11264
#define BM     (BBATCH*MTOK)  // 256
#define CPAD   11008          // 172*64 padded logits-col count
#define KCAT   1536           // concat-K for split-bf16 logits GEMM

__device__ __forceinline__ u16 f2bf(float f) {
    u32 u = __builtin_bit_cast(u32, f);
    u += 0x7fffu + ((u >> 16) & 1u);
    return (u16)(u >> 16);
}
__device__ __forceinline__ float bf2f(u16 h) {
    u32 u = ((u32)h) << 16;
    return __builtin_bit_cast(float, u);
}
__device__ __forceinline__ u32 pk2bf(float a, float b) {
    __hip_bfloat162 t = __float22bfloat162_rn(float2{a, b});
    u32 r;
    __builtin_memcpy(&r, &t, 4);
    return r;
}

// ---------------------------------------------------------------------------
// x -> xcat[256][1536] = [xh | xh | xl] bf16, plus xb = xh [256][512]
// ---------------------------------------------------------------------------
__global__ __launch_bounds__(256) void k_xcat(
    const float* __restrict__ x, u16* __restrict__ xcat, u16* __restrict__ xb) {
    int i = (blockIdx.x * 256 + threadIdx.x) * 4;
    int r = i >> 9, k = i & 511;
    float4 v = *(const float4*)&x[i];
    float a[4] = {v.x, v.y, v.z, v.w};
    u16 hh[4], ll[4];
    #pragma unroll
    for (int j = 0; j < 4; ++j) {
        hh[j] = f2bf(a[j]);
        ll[j] = f2bf(a[j] - bf2f(hh[j]));
    }
    uint2 hv = make_uint2((u32)hh[0] | ((u32)hh[1] << 16), (u32)hh[2] | ((u32)hh[3] << 16));
    uint2 lv = make_uint2((u32)ll[0] | ((u32)ll[1] << 16), (u32)ll[2] | ((u32)ll[3] << 16));
    *(uint2*)&xcat[r * KCAT + k]        = hv;
    *(uint2*)&xcat[r * KCAT + 512 + k]  = hv;
    *(uint2*)&xcat[r * KCAT + 1024 + k] = lv;
    *(uint2*)&xb[i] = hv;
}

// ---------------------------------------------------------------------------
// phi [512][10912] fp32 -> pcat[11008][1536] bf16 = [ph | pl | ph] per row
// grid (kt=8, ct=172)
// ---------------------------------------------------------------------------
__global__ __launch_bounds__(256) void k_t_phi(
    const float* __restrict__ phi, u16* __restrict__ pcat) {
    __shared__ float Ls[64][65];
    const int kt = blockIdx.x, ct = blockIdx.y;
    const int tid = threadIdx.x;
    {
        int r = tid >> 2, cg = (tid & 3) << 4;
        const float* src = phi + (size_t)(kt * 64 + r) * NHCOL + ct * 64 + cg;
        #pragma unroll
        for (int j = 0; j < 4; ++j) {
            int c0 = ct * 64 + cg + j * 4;
            float4 v = (c0 + 4 <= NHCOL) ? *(const float4*)&src[j * 4]
                                         : make_float4(0.f, 0.f, 0.f, 0.f);
            *(float4*)&Ls[r][cg + j * 4] = v;
        }
    }
    __syncthreads();
    {
        int cc = tid & 63, kq = tid >> 6;
        u16 th[16], tl[16];
        #pragma unroll
        for (int i = 0; i < 16; ++i) {
            float v = Ls[kq * 16 + i][cc];
            th[i] = f2bf(v);
            tl[i] = f2bf(v - bf2f(th[i]));
        }
        int k = kt * 64 + kq * 16;
        u16* row = pcat + (size_t)(ct * 64 + cc) * KCAT;
        *(uint4*)(row + k)            = *(uint4*)&th[0];
        *(uint4*)(row + k + 8)        = *(uint4*)&th[8];
        *(uint4*)(row + 1024 + k)     = *(uint4*)&th[0];
        *(uint4*)(row + 1024 + k + 8) = *(uint4*)&th[8];
        *(uint4*)(row + 512 + k)      = *(uint4*)&tl[0];
        *(uint4*)(row + 512 + k + 8)  = *(uint4*)&tl[8];
    }
}

// ---------------------------------------------------------------------------
// Concat-K MFMA GEMM: logits[256][10912] fp32 = xcat[256][1536] * pcat^T
// grid (ct=172): 256x64 tile, 4 waves of 64x64; pcat streamed exactly once.
// ---------------------------------------------------------------------------
__global__ __launch_bounds__(256) void k_lgemm(
    const u16* __restrict__ A, const u16* __restrict__ BT, float* __restrict__ C) {
    __shared__ u16 As[256 * 40];
    __shared__ u16 Bs[64 * 40];
    const int ct = blockIdx.x;
    const int tid = threadIdx.x;
    const int wv = tid >> 6, lane = tid & 63, quad = lane >> 4, l15 = lane & 15;
    f32x4 acc[4][4] = {};
    for (int kb = 0; kb < KCAT; kb += 32) {
        {
            const u16* s = A + (size_t)tid * KCAT + kb;
            #pragma unroll
            for (int j = 0; j < 4; ++j)
                *(uint4*)&As[tid * 40 + j * 8] = *(const uint4*)(s + j * 8);
            int r = tid >> 2, kg = (tid & 3) * 8;
            *(uint4*)&Bs[r * 40 + kg] =
                *(const uint4*)(BT + (size_t)(ct * 64 + r) * KCAT + kb + kg);
        }
        __syncthreads();
        bf16x8 af[4], bfr[4];
        #pragma unroll
        for (int i = 0; i < 4; ++i) {
            af[i]  = *(const bf16x8*)&As[(wv * 64 + i * 16 + l15) * 40 + quad * 8];
            bfr[i] = *(const bf16x8*)&Bs[(i * 16 + l15) * 40 + quad * 8];
        }
        #pragma unroll
        for (int i = 0; i < 4; ++i)
            #pragma unroll
            for (int j = 0; j < 4; ++j)
                acc[i][j] = __builtin_amdgcn_mfma_f32_16x16x32_bf16(af[i], bfr[j], acc[i][j], 0, 0, 0);
        __syncthreads();
    }
    #pragma unroll
    for (int j = 0; j < 4; ++j) {
        int col = ct * 64 + j * 16 + l15;
        if (col < NHCOL) {
            #pragma unroll
            for (int i = 0; i < 4; ++i) {
                int r0 = wv * 64 + i * 16 + quad * 4;
                #pragma unroll
                for (int r = 0; r < 4; ++r)
                    C[(size_t)(r0 + r) * NHCOL + col] = acc[i][j][r];
            }
        }
    }
}

// ---------------------------------------------------------------------------
// W1[16][512][682] -> W1T[n*704+h][k=512] bf16 (zero h>=682)
// ---------------------------------------------------------------------------
__global__ __launch_bounds__(256) void k_t_w1(const float* __restrict__ W1, u16* __restrict__ W1T) {
    __shared__ float Ls[64][65];
    const int kt = blockIdx.x, ht = blockIdx.y, n = blockIdx.z;
    const int tid = threadIdx.x;
    {
        int r = tid >> 2, cg = (tid & 3) << 4;
        const float* src = W1 + (size_t)(n * 512 + kt * 64 + r) * HDIM + ht * 64;
        #pragma unroll
        for (int i = 0; i < 16; ++i) {
            int c = cg + i, h = ht * 64 + c;
            Ls[r][c] = (h < HDIM) ? src[c] : 0.f;
        }
    }
    __syncthreads();
    {
        int cc = tid & 63, kq = tid >> 6;
        u16 tmp[16];
        #pragma unroll
        for (int i = 0; i < 16; ++i) tmp[i] = f2bf(Ls[kq * 16 + i][cc]);
        u16* dst = W1T + (size_t)(n * HPAD + ht * 64 + cc) * 512 + kt * 64 + kq * 16;
        *(uint4*)dst = *(uint4*)&tmp[0];
        *(uint4*)(dst + 8) = *(uint4*)&tmp[8];
    }
}

// ---------------------------------------------------------------------------
// W2[16][682][512] -> W2T[d][n*704+h] bf16 (zero h>=682)
// ---------------------------------------------------------------------------
__global__ __launch_bounds__(256) void k_t_w2(const float* __restrict__ W2, u16* __restrict__ W2T) {
    __shared__ float Ls[64][65];
    const int dt = blockIdx.x, ht = blockIdx.y, n = blockIdx.z;
    const int tid = threadIdx.x;
    {
        int r = tid >> 2, cg = (tid & 3) << 4;
        int h = ht * 64 + r;
        if (h < HDIM) {
            const float* src = W2 + (size_t)(n * HDIM + h) * 512 + dt * 64 + cg;
            float4 v0 = *(const float4*)&src[0];
            float4 v1 = *(const float4*)&src[4];
            float4 v2 = *(const float4*)&src[8];
            float4 v3 = *(const float4*)&src[12];
            *(float4*)&Ls[r][cg + 0]  = v0; *(float4*)&Ls[r][cg + 4]  = v1;
            *(float4*)&Ls[r][cg + 8]  = v2; *(float4*)&Ls[r][cg + 12] = v3;
        } else {
            #pragma unroll
            for (int i = 0; i < 16; ++i) Ls[r][cg + i] = 0.f;
        }
    }
    __syncthreads();
    {
        int cc = tid & 63, kq = tid >> 6;
        u16 tmp[16];
        #pragma unroll
        for (int i = 0; i < 16; ++i) tmp[i] = f2bf(Ls[kq * 16 + i][cc]);
        u16* dst = W2T + (size_t)(dt * 64 + cc) * NHPCOL + n * HPAD + ht * 64 + kq * 16;
        *(uint4*)dst = *(uint4*)&tmp[0];
        *(uint4*)(dst + 8) = *(uint4*)&tmp[8];
    }
}

// ---------------------------------------------------------------------------
// Wout[8192][512] -> WoutT[o][k] bf16
// ---------------------------------------------------------------------------
__global__ __launch_bounds__(256) void k_t_wout(const float* __restrict__ W, u16* __restrict__ WT) {
    __shared__ float Ls[64][65];
    const int kt = blockIdx.x, ot = blockIdx.y;
    const int tid = threadIdx.x;
    {
        int r = tid >> 2, cg = (tid & 3) << 4;
        const float* src = W + (size_t)(kt * 64 + r) * 512 + ot * 64 + cg;
        float4 v0 = *(const float4*)&src[0];
        float4 v1 = *(const float4*)&src[4];
        float4 v2 = *(const float4*)&src[8];
        float4 v3 = *(const float4*)&src[12];
        *(float4*)&Ls[r][cg + 0]  = v0; *(float4*)&Ls[r][cg + 4]  = v1;
        *(float4*)&Ls[r][cg + 8]  = v2; *(float4*)&Ls[r][cg + 12] = v3;
    }
    __syncthreads();
    {
        int cc = tid & 63, kq = tid >> 6;
        u16 tmp[16];
        #pragma unroll
        for (int i = 0; i < 16; ++i) tmp[i] = f2bf(Ls[kq * 16 + i][cc]);
        u16* dst = WT + (size_t)(ot * 64 + cc) * 8192 + kt * 64 + kq * 16;
        *(uint4*)dst = *(uint4*)&tmp[0];
        *(uint4*)(dst + 8) = *(uint4*)&tmp[8];
    }
}

// ---------------------------------------------------------------------------
// Dw softmax over m  ->  DwT[b][n][p(704, zero-pad)][16 m] bf16
// ---------------------------------------------------------------------------
__global__ __launch_bounds__(256) void k_dw(const float* __restrict__ L, u16* __restrict__ DwT) {
    const int b = blockIdx.y;
    const int c = blockIdx.x * 256 + threadIdx.x;      // n*704+p
    const int n = c / HPAD, p = c - n * HPAD;
    u16 o[16];
    if (p < HDIM) {
        float v[16];
        float mx = -1e30f;
        #pragma unroll
        for (int m = 0; m < 16; ++m) {
            v[m] = L[(b * 16 + m) * NHCOL + n * HDIM + p];
            mx = fmaxf(mx, v[m]);
        }
        float s = 0.f;
        #pragma unroll
        for (int m = 0; m < 16; ++m) { v[m] = expf(v[m] - mx); s += v[m]; }
        float inv = 1.f / s;
        #pragma unroll
        for (int m = 0; m < 16; ++m) o[m] = f2bf(v[m] * inv);
    } else {
        #pragma unroll
        for (int m = 0; m < 16; ++m) o[m] = 0;
    }
    u16* dst = DwT + (size_t)((b * 16 + n) * HPAD + p) * 16;
    *(uint4*)dst = *(uint4*)&o[0];
    *(uint4*)(dst + 8) = *(uint4*)&o[8];
}

// ---------------------------------------------------------------------------
// Cw = softmax_p(softmax_n(logits)) -> CwB[b][n][m][704 p] bf16 (zero-pad p)
// ---------------------------------------------------------------------------
__global__ __launch_bounds__(256) void k_cw(const float* __restrict__ L, u16* __restrict__ CwB) {
    const int m = blockIdx.x, b = blockIdx.y;
    __shared__ float row[NHCOL];
    const int tid = threadIdx.x;
    const float* Lrow = L + (size_t)(b * 16 + m) * NHCOL;
    for (int i = tid; i < NHCOL; i += 256) row[i] = Lrow[i];
    __syncthreads();
    for (int p = tid; p < HDIM; p += 256) {
        float v[16];
        float mx = -1e30f;
        #pragma unroll
        for (int n = 0; n < 16; ++n) { v[n] = row[n * HDIM + p]; mx = fmaxf(mx, v[n]); }
        float s = 0.f;
        #pragma unroll
        for (int n = 0; n < 16; ++n) { v[n] = expf(v[n] - mx); s += v[n]; }
        float inv = 1.f / s;
        #pragma unroll
        for (int n = 0; n < 16; ++n) row[n * HDIM + p] = expf(v[n] * inv);  // cache exp(s1)
    }
    __syncthreads();
    const int wv = tid >> 6, lane = tid & 63;
    for (int nn = 0; nn < 4; ++nn) {
        int n = wv * 4 + nn;
        float s = 0.f;
        for (int p = lane; p < HDIM; p += 64) s += row[n * HDIM + p];
        #pragma unroll
        for (int off = 32; off > 0; off >>= 1) s += __shfl_xor(s, off);
        float inv = 1.f / s;
        u16* dst = CwB + (size_t)(((b * 16 + n) * 16 + m)) * HPAD;
        for (int p = lane; p < HDIM; p += 64) dst[p] = f2bf(row[n * HDIM + p] * inv);
        if (lane < HPAD - HDIM) dst[HDIM + lane] = 0;
    }
}

// ---------------------------------------------------------------------------
// MFMA GEMM: T1b[256][11264] bf16 = xb[256][512] * W1T^T
// grid (ct=88, rt=2); 128x128 tile
// ---------------------------------------------------------------------------
__global__ __launch_bounds__(256) void k_t1gemm(
    const u16* __restrict__ A, const u16* __restrict__ BT, u16* __restrict__ C) {
    __shared__ u16 AsL[128 * 40];
    __shared__ u16 BsL[128 * 40];
    const int ct = blockIdx.x, rt = blockIdx.y;
    const int tid = threadIdx.x;
    const int wv = tid >> 6, lane = tid & 63, quad = lane >> 4, l15 = lane & 15;
    const int mb = (wv & 1) * 64, nb = (wv >> 1) * 64;
    f32x4 acc[4][4] = {};
    for (int kb = 0; kb < 512; kb += 32) {
        {
            int r = tid >> 1, kg = (tid & 1) * 16;
            const u16* s = A + (size_t)(rt * 128 + r) * 512 + kb + kg;
            *(uint4*)&AsL[r * 40 + kg]     = *(const uint4*)s;
            *(uint4*)&AsL[r * 40 + kg + 8] = *(const uint4*)(s + 8);
            const u16* t = BT + (size_t)(ct * 128 + r) * 512 + kb + kg;
            *(uint4*)&BsL[r * 40 + kg]     = *(const uint4*)t;
            *(uint4*)&BsL[r * 40 + kg + 8] = *(const uint4*)(t + 8);
        }
        __syncthreads();
        bf16x8 af[4], bfr[4];
        #pragma unroll
        for (int i = 0; i < 4; ++i) {
            af[i]  = *(const bf16x8*)&AsL[(mb + i * 16 + l15) * 40 + quad * 8];
            bfr[i] = *(const bf16x8*)&BsL[(nb + i * 16 + l15) * 40 + quad * 8];
        }
        #pragma unroll
        for (int i = 0; i < 4; ++i)
            #pragma unroll
            for (int j = 0; j < 4; ++j)
                acc[i][j] = __builtin_amdgcn_mfma_f32_16x16x32_bf16(af[i], bfr[j], acc[i][j], 0, 0, 0);
        __syncthreads();
    }
    #pragma unroll
    for (int i = 0; i < 4; ++i)
        #pragma unroll
        for (int j = 0; j < 4; ++j) {
            int col = ct * 128 + nb + j * 16 + l15;
            int r0  = rt * 128 + mb + i * 16 + quad * 4;
            #pragma unroll
            for (int r = 0; r < 4; ++r)
                C[(size_t)(r0 + r) * NHPCOL + col] = f2bf(acc[i][j][r]);
        }
}

// ---------------------------------------------------------------------------
// Fused middle (MFMA), rebuilt:
//  stage1: hmid[p][h] = relu(b1 + Dw^T·T1)  via 32x32x16 (K=16 exact, bias in C)
//  stage2: G[m][h] += Cw·hmid via 16x16x32
// hmidT in LDS with 16B-granule XOR swizzle (stride 64, conflict-minimal).
// Each wave owns 32 h rows -> no barriers in the chunk loop.
// grid (6, 16, 16)
// ---------------------------------------------------------------------------
__global__ __launch_bounds__(256) void k_mid(
    const u16* __restrict__ T1b, const u16* __restrict__ DwT,
    const u16* __restrict__ CwB, const float* __restrict__ b1,
    u16* __restrict__ Gb) {
    __shared__ u16 T1T[128 * 24];      // [h-local][m], stride 24 (16B-aligned rows)
    __shared__ u16 hmidT[128 * 64];    // [h-local][64 p], XOR-swizzled 16B granules
    const int ht = blockIdx.x, n = blockIdx.y, b = blockIdx.z;
    const int tid = threadIdx.x;
    const int wv = tid >> 6, lane = tid & 63;
    const int quad = lane >> 4, l15 = lane & 15;
    const int l31 = lane & 31, half = lane >> 5;
    const int h0 = ht * 128;
    const int b16n = b * 16 + n;

    // stage T1 tile [16 m][128 h] -> T1T[h][m]
    {
        int m = tid & 15, hh0 = (tid >> 4) * 8;
        u16 v[8];
        if (h0 + hh0 + 8 <= HPAD) {
            *(uint4*)v = *(const uint4*)(T1b + (size_t)(b * 16 + m) * NHPCOL + n * HPAD + h0 + hh0);
        } else {
            #pragma unroll
            for (int i = 0; i < 8; ++i) v[i] = 0;
        }
        #pragma unroll
        for (int i = 0; i < 8; ++i) T1T[(hh0 + i) * 24 + m] = v[i];
    }
    __syncthreads();

    // stage1 B-frag (constant across chunks): B[k=m][col=h], col=l31, k=half*8+j
    const int hrow = wv * 32 + l31;                       // this lane's h for stage1
    bf16x8 bt1 = *(const bf16x8*)&T1T[hrow * 24 + half * 8];
    int hg1 = h0 + hrow;
    float biasf = (hg1 < HDIM) ? b1[n * HDIM + hg1] : 0.f;
    f32x16 cbias;
    #pragma unroll
    for (int i = 0; i < 16; ++i) cbias[i] = biasf;

    const u16* dwbase = DwT + (size_t)(b16n * HPAD) * 16;
    const u16* cwrow  = CwB + (size_t)(b16n * 16 + l15) * HPAD;

    f32x4 acc[2] = {};
    const int hsw = hrow & 7;
    for (int c = 0; c < 11; ++c) {
        const int p0 = c * 64;
        // ---- stage1: 2 p-tiles of 32 ----
        #pragma unroll
        for (int pt = 0; pt < 2; ++pt) {
            // A[row=p][k=m]: row=l31, k=half*8+j  -> coalesced 16B global load
            bf16x8 adw = *(const bf16x8*)(dwbase + (size_t)(p0 + pt * 32 + l31) * 16 + half * 8);
            f32x16 hm = __builtin_amdgcn_mfma_f32_32x32x16_bf16(adw, bt1, cbias, 0, 0, 0);
            // C/D: col=l31(h), row = (r&3) + 8*(r>>2) + 4*half
            #pragma unroll
            for (int g = 0; g < 4; ++g) {
                float v0 = fmaxf(hm[g * 4 + 0], 0.f);
                float v1 = fmaxf(hm[g * 4 + 1], 0.f);
                float v2 = fmaxf(hm[g * 4 + 2], 0.f);
                float v3 = fmaxf(hm[g * 4 + 3], 0.f);
                uint2 pk = make_uint2(pk2bf(v0, v1), pk2bf(v2, v3));
                int gran = (pt * 4 + g) ^ hsw;
                *(uint2*)&hmidT[hrow * 64 + gran * 8 + half * 4] = pk;
            }
        }
        // ---- stage2: 2 k-slices of 32 p, 2 h-tiles of 16 ----
        #pragma unroll
        for (int s = 0; s < 2; ++s) {
            bf16x8 acw = *(const bf16x8*)(cwrow + p0 + s * 32 + quad * 8);
            #pragma unroll
            for (int hj = 0; hj < 2; ++hj) {
                int hr = wv * 32 + hj * 16 + l15;
                int gr = (s * 4 + quad) ^ (hr & 7);
                bf16x8 bh = *(const bf16x8*)&hmidT[hr * 64 + gr * 8];
                acc[hj] = __builtin_amdgcn_mfma_f32_16x16x32_bf16(acw, bh, acc[hj], 0, 0, 0);
            }
        }
    }
    // epilogue: G bf16  (C-layout: col=h=l15, row=m=quad*4+r)
    #pragma unroll
    for (int hj = 0; hj < 2; ++hj) {
        int h = h0 + wv * 32 + hj * 16 + l15;
        if (h < HPAD) {
            #pragma unroll
            for (int r = 0; r < 4; ++r) {
                int m = quad * 4 + r;
                Gb[(size_t)(b * 16 + m) * NHPCOL + n * HPAD + h] = f2bf(acc[hj][r]);
            }
        }
    }
}

// ---------------------------------------------------------------------------
// Init: Y[bm][d] = sum_n b2[n][d];  out[b][o] = bout[o]
// ---------------------------------------------------------------------------
__global__ __launch_bounds__(256) void k_init(
    const float* __restrict__ b2, const float* __restrict__ bout,
    float* __restrict__ Y, float* __restrict__ out) {
    const int bid = blockIdx.x, tid = threadIdx.x;
    if (bid < 512) {
        int idx = bid * 256 + tid;
        int d = idx & 511;
        float s = 0.f;
        #pragma unroll
        for (int nn = 0; nn < 16; ++nn) s += b2[nn * 512 + d];
        Y[idx] = s;
    } else {
        int idx = (bid - 512) * 256 + tid;
        out[idx] = bout[idx & 511];
    }
}

// ---------------------------------------------------------------------------
// MFMA split-K GEMM: Y[256][512] += Gb[.., n-slice] * W2T[d][n-slice]^T
// grid (ct=4, rt=4, n=16)
// ---------------------------------------------------------------------------
__global__ __launch_bounds__(256) void k_ygemm(
    const u16* __restrict__ G, const u16* __restrict__ W2T, float* __restrict__ Y) {
    __shared__ u16 AsL[64 * 40];
    __shared__ u16 BsL[128 * 40];
    const int ct = blockIdx.x, rt = blockIdx.y, n = blockIdx.z;
    const int tid = threadIdx.x;
    const int wv = tid >> 6, lane = tid & 63, quad = lane >> 4, l15 = lane & 15;
    const int m0 = rt * 64, d0 = ct * 128;
    f32x4 acc[4][2] = {};
    for (int kb = 0; kb < HPAD; kb += 32) {
        {
            int am = tid >> 2, akg = (tid & 3) * 8;
            *(uint4*)&AsL[am * 40 + akg] =
                *(const uint4*)(G + (size_t)(m0 + am) * NHPCOL + n * HPAD + kb + akg);
            int bc = tid >> 1, bkg = (tid & 1) * 16;
            const u16* t = W2T + (size_t)(d0 + bc) * NHPCOL + n * HPAD + kb + bkg;
            *(uint4*)&BsL[bc * 40 + bkg]     = *(const uint4*)t;
            *(uint4*)&BsL[bc * 40 + bkg + 8] = *(const uint4*)(t + 8);
        }
        __syncthreads();
        bf16x8 af[4], bfr[2];
        #pragma unroll
        for (int i = 0; i < 4; ++i) af[i] = *(const bf16x8*)&AsL[(i * 16 + l15) * 40 + quad * 8];
        #pragma unroll
        for (int j = 0; j < 2; ++j) bfr[j] = *(const bf16x8*)&BsL[(wv * 32 + j * 16 + l15) * 40 + quad * 8];
        #pragma unroll
        for (int i = 0; i < 4; ++i)
            #pragma unroll
            for (int j = 0; j < 2; ++j)
                acc[i][j] = __builtin_amdgcn_mfma_f32_16x16x32_bf16(af[i], bfr[j], acc[i][j], 0, 0, 0);
        __syncthreads();
    }
    #pragma unroll
    for (int i = 0; i < 4; ++i)
        #pragma unroll
        for (int j = 0; j < 2; ++j) {
            int d = d0 + wv * 32 + j * 16 + l15;
            int r0 = m0 + i * 16 + quad * 4;
            #pragma unroll
            for (int r = 0; r < 4; ++r)
                atomicAdd(&Y[(size_t)(r0 + r) * 512 + d], acc[i][j][r]);
        }
}

// ---------------------------------------------------------------------------
// MFMA split-K GEMM: out[16][512] += Yflat[16][k-slice] * WoutT[o][k-slice]^T
// grid (ct=4, ks=16)
// ---------------------------------------------------------------------------
__global__ __launch_bounds__(256) void k_outgemm(
    const float* __restrict__ Y, const u16* __restrict__ WoutT, float* __restrict__ out) {
    __shared__ u16 AsL[16 * 40];
    __shared__ u16 BsL[128 * 40];
    const int ct = blockIdx.x, ks = blockIdx.y;
    const int tid = threadIdx.x;
    const int wv = tid >> 6, lane = tid & 63, quad = lane >> 4, l15 = lane & 15;
    const int o0 = ct * 128, kbase = ks * 512;
    f32x4 acc[2] = {};
    for (int kb = 0; kb < 512; kb += 32) {
        {
            int r = tid >> 4, k2 = (tid & 15) * 2;
            float2 v = *(const float2*)&Y[(size_t)r * 8192 + kbase + kb + k2];
            AsL[r * 40 + k2]     = f2bf(v.x);
            AsL[r * 40 + k2 + 1] = f2bf(v.y);
            int bc = tid >> 1, bkg = (tid & 1) * 16;
            const u16* t = WoutT + (size_t)(o0 + bc) * 8192 + kbase + kb + bkg;
            *(uint4*)&BsL[bc * 40 + bkg]     = *(const uint4*)t;
            *(uint4*)&BsL[bc * 40 + bkg + 8] = *(const uint4*)(t + 8);
        }
        __syncthreads();
        bf16x8 af = *(const bf16x8*)&AsL[l15 * 40 + quad * 8];
        #pragma unroll
        for (int j = 0; j < 2; ++j) {
            bf16x8 bfr = *(const bf16x8*)&BsL[(wv * 32 + j * 16 + l15) * 40 + quad * 8];
            acc[j] = __builtin_amdgcn_mfma_f32_16x16x32_bf16(af, bfr, acc[j], 0, 0, 0);
        }
        __syncthreads();
    }
    #pragma unroll
    for (int j = 0; j < 2; ++j) {
        int o = o0 + wv * 32 + j * 16 + l15;
        #pragma unroll
        for (int r = 0; r < 4; ++r)
            atomicAdd(&out[(size_t)(quad * 4 + r) * 512 + o], acc[j][r]);
    }
}

// ---------------------------------------------------------------------------
extern "C" void kernel_launch(void* const* d_in, const int* in_sizes, int n_in,
                              void* d_out, int out_size, void* d_ws, size_t ws_size,
                              hipStream_t stream) {
    const float* x    = (const float*)d_in[0];
    const float* phi  = (const float*)d_in[1];
    const float* W1   = (const float*)d_in[2];
    const float* b1   = (const float*)d_in[3];
    const float* W2   = (const float*)d_in[4];
    const float* b2   = (const float*)d_in[5];
    const float* Wout = (const float*)d_in[6];
    const float* bout = (const float*)d_in[7];
    float* out = (float*)d_out;

    // Workspace layout with lifetime-based aliasing (peak 66,748,416 B):
    //  [0, 11.17M)          logits (live steps 3-5); Y aliases at 0 (live 11-13)
    //  [11.17M, 44.99M)     pcat (live 2-3); after: DwT, CwB, W1T, T1b, Gb
    //  [45.78M, 46.56M)     xcat (live 1-3)
    //  [46.56M, 46.83M)     xb (live 1-7)
    //  [46.83M, 58.36M)     W2T;  [58.36M, 66.75M) WoutT
    char* base = (char*)d_ws;
    float* logits = (float*)(base + 0);
    u16*   pcat   = (u16*)(base + 11173888);      // 33,816,576 (transient)
    u16*   DwT    = (u16*)(base + 11173888);      //  5,767,168
    u16*   CwB    = (u16*)(base + 16941056);      //  5,767,168
    u16*   W1T    = (u16*)(base + 22708224);      // 11,534,336 -> 34,242,560
    u16*   T1b    = (u16*)(base + 34242560);      //  5,767,168 -> 40,009,728
    u16*   Gb     = (u16*)(base + 40009728);      //  5,767,168 -> 45,776,896
    u16*   xcat   = (u16*)(base + 45776896);      //    786,432 -> 46,563,328
    u16*   xb     = (u16*)(base + 46563328);      //    262,144 -> 46,825,472
    u16*   W2T    = (u16*)(base + 46825472);      // 11,534,336 -> 58,359,808
    u16*   WoutT  = (u16*)(base + 58359808);      //  8,388,608 -> 66,748,416
    float* Y      = (float*)(base + 0);           //    524,288 (aliases dead logits)

    k_xcat    <<<dim3(128), 256, 0, stream>>>(x, xcat, xb);
    k_t_phi   <<<dim3(8, 172), 256, 0, stream>>>(phi, pcat);
    k_lgemm   <<<dim3(172), 256, 0, stream>>>(xcat, pcat, logits);
    k_dw      <<<dim3(44, 16), 256, 0, stream>>>(logits, DwT);
    k_cw      <<<dim3(16, 16), 256, 0, stream>>>(logits, CwB);
    k_t_w1    <<<dim3(8, 11, 16), 256, 0, stream>>>(W1, W1T);
    k_t1gemm  <<<dim3(88, 2), 256, 0, stream>>>(xb, W1T, T1b);
    k_mid     <<<dim3(6, 16, 16), 256, 0, stream>>>(T1b, DwT, CwB, b1, Gb);
    k_t_w2    <<<dim3(8, 11, 16), 256, 0, stream>>>(W2, W2T);
    k_t_wout  <<<dim3(128, 8), 256, 0, stream>>>(Wout, WoutT);
    k_init    <<<dim3(544), 256, 0, stream>>>(b2, bout, Y, out);
    k_ygemm   <<<dim3(4, 4, 16), 256, 0, stream>>>(Gb, W2T, Y);
    k_outgemm <<<dim3(4, 16), 256, 0, stream>>>(Y, WoutT, out);
}

// Round 8
// 272.159 us; speedup vs baseline: 1.1714x; 1.1714x over previous
//
#include <hip/hip_runtime.h>
#include <hip/hip_bf16.h>
#include <math.h>

typedef unsigned int   u32;
typedef unsigned short u16;
typedef __bf16 bf16;
typedef bf16  bf16x8  __attribute__((ext_vector_type(8)));
typedef float f32x4   __attribute__((ext_vector_type(4)));
typedef float f32x16  __attribute__((ext_vector_type(16)));

#define BBATCH 16
#define MTOK   16
#define NEXP   16
#define DDIM   512
#define HDIM   682
#define HPAD   704            // 11*64
#define NHCOL  (NEXP*HDIM)    // 10912
#define NHPCOL (NEXP*HPAD)    // 11264
#define BM     (BBATCH*MTOK)  // 256
#define CPAD   10944          // 171*64 padded logits-col count

__device__ __forceinline__ u16 f2bf(float f) {
    u32 u = __builtin_bit_cast(u32, f);
    u += 0x7fffu + ((u >> 16) & 1u);
    return (u16)(u >> 16);
}
__device__ __forceinline__ float bf2f(u16 h) {
    u32 u = ((u32)h) << 16;
    return __builtin_bit_cast(float, u);
}
__device__ __forceinline__ u32 pk2bf(float a, float b) {
    __hip_bfloat162 t = __float22bfloat162_rn(float2{a, b});
    u32 r;
    __builtin_memcpy(&r, &t, 4);
    return r;
}

// ---------------------------------------------------------------------------
// k_prep: ALL independent prep work in ONE launch (5880 blocks):
//  [0,1368)     phi -> ph/pl bf16 planes [10944][512]
//  [1368,2776)  W1 -> W1T[n*704+h][512]
//  [2776,4184)  W2 -> W2T[d][n*704+h]
//  [4184,5208)  Wout -> WoutT[o][8192]
//  [5208,5336)  x -> xh, xl
//  [5336,5880)  Y = sum_n b2 ; out = bout
// ---------------------------------------------------------------------------
__global__ __launch_bounds__(256) void k_prep(
    const float* __restrict__ x, const float* __restrict__ phi,
    const float* __restrict__ W1, const float* __restrict__ W2,
    const float* __restrict__ Wout, const float* __restrict__ b2,
    const float* __restrict__ bout,
    u16* __restrict__ ph, u16* __restrict__ pl,
    u16* __restrict__ W1T, u16* __restrict__ W2T, u16* __restrict__ WoutT,
    u16* __restrict__ xh, u16* __restrict__ xl,
    float* __restrict__ Y, float* __restrict__ out) {
    __shared__ float Ls[64][65];
    const int bid = blockIdx.x, tid = threadIdx.x;

    if (bid < 1368) {
        // ---- phi transpose + hi/lo split: kt = bid&7, ct = bid>>3 ----
        const int kt = bid & 7, ct = bid >> 3;
        {
            int r = tid >> 2, cg = (tid & 3) << 4;
            const float* src = phi + (size_t)(kt * 64 + r) * NHCOL + ct * 64 + cg;
            #pragma unroll
            for (int j = 0; j < 4; ++j) {
                int c0 = ct * 64 + cg + j * 4;
                float4 v = (c0 + 4 <= NHCOL) ? *(const float4*)&src[j * 4]
                                             : make_float4(0.f, 0.f, 0.f, 0.f);
                *(float4*)&Ls[r][cg + j * 4] = v;
            }
        }
        __syncthreads();
        {
            int cc = tid & 63, kq = tid >> 6;
            u16 th[16], tl[16];
            #pragma unroll
            for (int i = 0; i < 16; ++i) {
                float v = Ls[kq * 16 + i][cc];
                th[i] = f2bf(v);
                tl[i] = f2bf(v - bf2f(th[i]));
            }
            size_t off = (size_t)(ct * 64 + cc) * 512 + kt * 64 + kq * 16;
            *(uint4*)(ph + off)     = *(uint4*)&th[0];
            *(uint4*)(ph + off + 8) = *(uint4*)&th[8];
            *(uint4*)(pl + off)     = *(uint4*)&tl[0];
            *(uint4*)(pl + off + 8) = *(uint4*)&tl[8];
        }
    } else if (bid < 2776) {
        // ---- W1 transpose ----
        int i = bid - 1368;
        const int kt = i & 7, r2 = i >> 3, ht = r2 % 11, n = r2 / 11;
        {
            int r = tid >> 2, cg = (tid & 3) << 4;
            const float* src = W1 + (size_t)(n * 512 + kt * 64 + r) * HDIM + ht * 64;
            #pragma unroll
            for (int q = 0; q < 16; ++q) {
                int c = cg + q, h = ht * 64 + c;
                Ls[r][c] = (h < HDIM) ? src[c] : 0.f;
            }
        }
        __syncthreads();
        {
            int cc = tid & 63, kq = tid >> 6;
            u16 tmp[16];
            #pragma unroll
            for (int q = 0; q < 16; ++q) tmp[q] = f2bf(Ls[kq * 16 + q][cc]);
            u16* dst = W1T + (size_t)(n * HPAD + ht * 64 + cc) * 512 + kt * 64 + kq * 16;
            *(uint4*)dst = *(uint4*)&tmp[0];
            *(uint4*)(dst + 8) = *(uint4*)&tmp[8];
        }
    } else if (bid < 4184) {
        // ---- W2 transpose ----
        int i = bid - 2776;
        const int dt = i & 7, r2 = i >> 3, ht = r2 % 11, n = r2 / 11;
        {
            int r = tid >> 2, cg = (tid & 3) << 4;
            int h = ht * 64 + r;
            if (h < HDIM) {
                const float* src = W2 + (size_t)(n * HDIM + h) * 512 + dt * 64 + cg;
                *(float4*)&Ls[r][cg + 0]  = *(const float4*)&src[0];
                *(float4*)&Ls[r][cg + 4]  = *(const float4*)&src[4];
                *(float4*)&Ls[r][cg + 8]  = *(const float4*)&src[8];
                *(float4*)&Ls[r][cg + 12] = *(const float4*)&src[12];
            } else {
                #pragma unroll
                for (int q = 0; q < 16; ++q) Ls[r][cg + q] = 0.f;
            }
        }
        __syncthreads();
        {
            int cc = tid & 63, kq = tid >> 6;
            u16 tmp[16];
            #pragma unroll
            for (int q = 0; q < 16; ++q) tmp[q] = f2bf(Ls[kq * 16 + q][cc]);
            u16* dst = W2T + (size_t)(dt * 64 + cc) * NHPCOL + n * HPAD + ht * 64 + kq * 16;
            *(uint4*)dst = *(uint4*)&tmp[0];
            *(uint4*)(dst + 8) = *(uint4*)&tmp[8];
        }
    } else if (bid < 5208) {
        // ---- Wout transpose ----
        int i = bid - 4184;
        const int kt = i & 127, ot = i >> 7;
        {
            int r = tid >> 2, cg = (tid & 3) << 4;
            const float* src = Wout + (size_t)(kt * 64 + r) * 512 + ot * 64 + cg;
            *(float4*)&Ls[r][cg + 0]  = *(const float4*)&src[0];
            *(float4*)&Ls[r][cg + 4]  = *(const float4*)&src[4];
            *(float4*)&Ls[r][cg + 8]  = *(const float4*)&src[8];
            *(float4*)&Ls[r][cg + 12] = *(const float4*)&src[12];
        }
        __syncthreads();
        {
            int cc = tid & 63, kq = tid >> 6;
            u16 tmp[16];
            #pragma unroll
            for (int q = 0; q < 16; ++q) tmp[q] = f2bf(Ls[kq * 16 + q][cc]);
            u16* dst = WoutT + (size_t)(ot * 64 + cc) * 8192 + kt * 64 + kq * 16;
            *(uint4*)dst = *(uint4*)&tmp[0];
            *(uint4*)(dst + 8) = *(uint4*)&tmp[8];
        }
    } else if (bid < 5336) {
        // ---- x hi/lo split ----
        int i = ((bid - 5208) * 256 + tid) * 4;
        float4 v = *(const float4*)&x[i];
        float a[4] = {v.x, v.y, v.z, v.w};
        u16 hh[4], ll[4];
        #pragma unroll
        for (int j = 0; j < 4; ++j) {
            hh[j] = f2bf(a[j]);
            ll[j] = f2bf(a[j] - bf2f(hh[j]));
        }
        *(uint2*)&xh[i] = make_uint2((u32)hh[0] | ((u32)hh[1] << 16), (u32)hh[2] | ((u32)hh[3] << 16));
        *(uint2*)&xl[i] = make_uint2((u32)ll[0] | ((u32)ll[1] << 16), (u32)ll[2] | ((u32)ll[3] << 16));
    } else {
        // ---- Y / out init ----
        int i = bid - 5336;
        if (i < 512) {
            int idx = i * 256 + tid;
            int d = idx & 511;
            float s = 0.f;
            #pragma unroll
            for (int nn = 0; nn < 16; ++nn) s += b2[nn * 512 + d];
            Y[idx] = s;
        } else {
            int idx = (i - 512) * 256 + tid;
            out[idx] = bout[idx & 511];
        }
    }
}

// ---------------------------------------------------------------------------
// Split-bf16 MFMA GEMM (R5-proven shape): logits[256][10912] fp32 =
//   (xh+xl)[256][512] * (ph+pl)^T   (3-product decomposition)
// grid (ct=171, rt=4); 64x64 tile, 4 waves of 16x64
// ---------------------------------------------------------------------------
__global__ __launch_bounds__(256) void k_lgemm(
    const u16* __restrict__ xh, const u16* __restrict__ xl,
    const u16* __restrict__ ph, const u16* __restrict__ pl,
    float* __restrict__ C) {
    __shared__ u16 AH[64 * 40], AL[64 * 40], BH[64 * 40], BL[64 * 40];
    const int ct = blockIdx.x, rt = blockIdx.y;
    const int tid = threadIdx.x;
    const int wv = tid >> 6, lane = tid & 63, quad = lane >> 4, l15 = lane & 15;
    f32x4 acc[4] = {};
    for (int kb = 0; kb < 512; kb += 32) {
        {
            int r = tid >> 2, kg = (tid & 3) * 8;
            size_t ao = (size_t)(rt * 64 + r) * 512 + kb + kg;
            size_t bo = (size_t)(ct * 64 + r) * 512 + kb + kg;
            *(uint4*)&AH[r * 40 + kg] = *(const uint4*)(xh + ao);
            *(uint4*)&AL[r * 40 + kg] = *(const uint4*)(xl + ao);
            *(uint4*)&BH[r * 40 + kg] = *(const uint4*)(ph + bo);
            *(uint4*)&BL[r * 40 + kg] = *(const uint4*)(pl + bo);
        }
        __syncthreads();
        bf16x8 ah = *(const bf16x8*)&AH[(wv * 16 + l15) * 40 + quad * 8];
        bf16x8 al = *(const bf16x8*)&AL[(wv * 16 + l15) * 40 + quad * 8];
        #pragma unroll
        for (int j = 0; j < 4; ++j) {
            bf16x8 bh = *(const bf16x8*)&BH[(j * 16 + l15) * 40 + quad * 8];
            bf16x8 bl = *(const bf16x8*)&BL[(j * 16 + l15) * 40 + quad * 8];
            acc[j] = __builtin_amdgcn_mfma_f32_16x16x32_bf16(ah, bh, acc[j], 0, 0, 0);
            acc[j] = __builtin_amdgcn_mfma_f32_16x16x32_bf16(ah, bl, acc[j], 0, 0, 0);
            acc[j] = __builtin_amdgcn_mfma_f32_16x16x32_bf16(al, bh, acc[j], 0, 0, 0);
        }
        __syncthreads();
    }
    #pragma unroll
    for (int j = 0; j < 4; ++j) {
        int col = ct * 64 + j * 16 + l15;
        if (col < NHCOL) {
            int r0 = rt * 64 + wv * 16 + quad * 4;
            #pragma unroll
            for (int r = 0; r < 4; ++r)
                C[(size_t)(r0 + r) * NHCOL + col] = acc[j][r];
        }
    }
}

// ---------------------------------------------------------------------------
// k_softmax (one launch, 960 blocks):
//  [0,704)   Dw: softmax over m -> DwT[b][n][p pad704][16 m] bf16
//  [704,960) Cw: softmax_p(softmax_n) -> CwB[b][n][m][704 p] bf16
// ---------------------------------------------------------------------------
__global__ __launch_bounds__(256) void k_softmax(
    const float* __restrict__ L, u16* __restrict__ DwT, u16* __restrict__ CwB) {
    __shared__ float row[NHCOL];
    const int bid = blockIdx.x, tid = threadIdx.x;
    if (bid < 704) {
        const int b = bid / 44;
        const int c = (bid % 44) * 256 + tid;          // n*704+p
        const int n = c / HPAD, p = c - n * HPAD;
        u16 o[16];
        if (p < HDIM) {
            float v[16];
            float mx = -1e30f;
            #pragma unroll
            for (int m = 0; m < 16; ++m) {
                v[m] = L[(b * 16 + m) * NHCOL + n * HDIM + p];
                mx = fmaxf(mx, v[m]);
            }
            float s = 0.f;
            #pragma unroll
            for (int m = 0; m < 16; ++m) { v[m] = expf(v[m] - mx); s += v[m]; }
            float inv = 1.f / s;
            #pragma unroll
            for (int m = 0; m < 16; ++m) o[m] = f2bf(v[m] * inv);
        } else {
            #pragma unroll
            for (int m = 0; m < 16; ++m) o[m] = 0;
        }
        u16* dst = DwT + (size_t)((b * 16 + n) * HPAD + p) * 16;
        *(uint4*)dst = *(uint4*)&o[0];
        *(uint4*)(dst + 8) = *(uint4*)&o[8];
    } else {
        const int j = bid - 704;
        const int m = j & 15, b = j >> 4;
        const float* Lrow = L + (size_t)(b * 16 + m) * NHCOL;
        for (int i = tid; i < NHCOL; i += 256) row[i] = Lrow[i];
        __syncthreads();
        for (int p = tid; p < HDIM; p += 256) {
            float v[16];
            float mx = -1e30f;
            #pragma unroll
            for (int n = 0; n < 16; ++n) { v[n] = row[n * HDIM + p]; mx = fmaxf(mx, v[n]); }
            float s = 0.f;
            #pragma unroll
            for (int n = 0; n < 16; ++n) { v[n] = expf(v[n] - mx); s += v[n]; }
            float inv = 1.f / s;
            #pragma unroll
            for (int n = 0; n < 16; ++n) row[n * HDIM + p] = expf(v[n] * inv);  // cache exp(s1)
        }
        __syncthreads();
        const int wv = tid >> 6, lane = tid & 63;
        for (int nn = 0; nn < 4; ++nn) {
            int n = wv * 4 + nn;
            float s = 0.f;
            for (int p = lane; p < HDIM; p += 64) s += row[n * HDIM + p];
            #pragma unroll
            for (int off = 32; off > 0; off >>= 1) s += __shfl_xor(s, off);
            float inv = 1.f / s;
            u16* dst = CwB + (size_t)(((b * 16 + n) * 16 + m)) * HPAD;
            for (int p = lane; p < HDIM; p += 64) dst[p] = f2bf(row[n * HDIM + p] * inv);
            if (lane < HPAD - HDIM) dst[HDIM + lane] = 0;
        }
    }
}

// ---------------------------------------------------------------------------
// MFMA GEMM: T1b[256][11264] bf16 = xh[256][512] * W1T^T
// grid (ct=88, rt=2); 128x128 tile
// ---------------------------------------------------------------------------
__global__ __launch_bounds__(256) void k_t1gemm(
    const u16* __restrict__ A, const u16* __restrict__ BT, u16* __restrict__ C) {
    __shared__ u16 AsL[128 * 40];
    __shared__ u16 BsL[128 * 40];
    const int ct = blockIdx.x, rt = blockIdx.y;
    const int tid = threadIdx.x;
    const int wv = tid >> 6, lane = tid & 63, quad = lane >> 4, l15 = lane & 15;
    const int mb = (wv & 1) * 64, nb = (wv >> 1) * 64;
    f32x4 acc[4][4] = {};
    for (int kb = 0; kb < 512; kb += 32) {
        {
            int r = tid >> 1, kg = (tid & 1) * 16;
            const u16* s = A + (size_t)(rt * 128 + r) * 512 + kb + kg;
            *(uint4*)&AsL[r * 40 + kg]     = *(const uint4*)s;
            *(uint4*)&AsL[r * 40 + kg + 8] = *(const uint4*)(s + 8);
            const u16* t = BT + (size_t)(ct * 128 + r) * 512 + kb + kg;
            *(uint4*)&BsL[r * 40 + kg]     = *(const uint4*)t;
            *(uint4*)&BsL[r * 40 + kg + 8] = *(const uint4*)(t + 8);
        }
        __syncthreads();
        bf16x8 af[4], bfr[4];
        #pragma unroll
        for (int i = 0; i < 4; ++i) {
            af[i]  = *(const bf16x8*)&AsL[(mb + i * 16 + l15) * 40 + quad * 8];
            bfr[i] = *(const bf16x8*)&BsL[(nb + i * 16 + l15) * 40 + quad * 8];
        }
        #pragma unroll
        for (int i = 0; i < 4; ++i)
            #pragma unroll
            for (int j = 0; j < 4; ++j)
                acc[i][j] = __builtin_amdgcn_mfma_f32_16x16x32_bf16(af[i], bfr[j], acc[i][j], 0, 0, 0);
        __syncthreads();
    }
    #pragma unroll
    for (int i = 0; i < 4; ++i)
        #pragma unroll
        for (int j = 0; j < 4; ++j) {
            int col = ct * 128 + nb + j * 16 + l15;
            int r0  = rt * 128 + mb + i * 16 + quad * 4;
            #pragma unroll
            for (int r = 0; r < 4; ++r)
                C[(size_t)(r0 + r) * NHPCOL + col] = f2bf(acc[i][j][r]);
        }
}

// ---------------------------------------------------------------------------
// Fused middle (MFMA):
//  stage1: hmid[p][h] = relu(b1 + Dw^T·T1)  via 32x32x16 (K=16 exact, bias in C)
//  stage2: G[m][h] += Cw·hmid via 16x16x32
// hmidT XOR-swizzled; waves own h-rows -> no barriers in chunk loop.
// grid (6, 16, 16)
// ---------------------------------------------------------------------------
__global__ __launch_bounds__(256) void k_mid(
    const u16* __restrict__ T1b, const u16* __restrict__ DwT,
    const u16* __restrict__ CwB, const float* __restrict__ b1,
    u16* __restrict__ Gb) {
    __shared__ u16 T1T[128 * 24];
    __shared__ u16 hmidT[128 * 64];
    const int ht = blockIdx.x, n = blockIdx.y, b = blockIdx.z;
    const int tid = threadIdx.x;
    const int wv = tid >> 6, lane = tid & 63;
    const int quad = lane >> 4, l15 = lane & 15;
    const int l31 = lane & 31, half = lane >> 5;
    const int h0 = ht * 128;
    const int b16n = b * 16 + n;

    {
        int m = tid & 15, hh0 = (tid >> 4) * 8;
        u16 v[8];
        if (h0 + hh0 + 8 <= HPAD) {
            *(uint4*)v = *(const uint4*)(T1b + (size_t)(b * 16 + m) * NHPCOL + n * HPAD + h0 + hh0);
        } else {
            #pragma unroll
            for (int i = 0; i < 8; ++i) v[i] = 0;
        }
        #pragma unroll
        for (int i = 0; i < 8; ++i) T1T[(hh0 + i) * 24 + m] = v[i];
    }
    __syncthreads();

    const int hrow = wv * 32 + l31;
    bf16x8 bt1 = *(const bf16x8*)&T1T[hrow * 24 + half * 8];
    int hg1 = h0 + hrow;
    float biasf = (hg1 < HDIM) ? b1[n * HDIM + hg1] : 0.f;
    f32x16 cbias;
    #pragma unroll
    for (int i = 0; i < 16; ++i) cbias[i] = biasf;

    const u16* dwbase = DwT + (size_t)(b16n * HPAD) * 16;
    const u16* cwrow  = CwB + (size_t)(b16n * 16 + l15) * HPAD;

    f32x4 acc[2] = {};
    const int hsw = hrow & 7;
    for (int c = 0; c < 11; ++c) {
        const int p0 = c * 64;
        #pragma unroll
        for (int pt = 0; pt < 2; ++pt) {
            bf16x8 adw = *(const bf16x8*)(dwbase + (size_t)(p0 + pt * 32 + l31) * 16 + half * 8);
            f32x16 hm = __builtin_amdgcn_mfma_f32_32x32x16_bf16(adw, bt1, cbias, 0, 0, 0);
            #pragma unroll
            for (int g = 0; g < 4; ++g) {
                float v0 = fmaxf(hm[g * 4 + 0], 0.f);
                float v1 = fmaxf(hm[g * 4 + 1], 0.f);
                float v2 = fmaxf(hm[g * 4 + 2], 0.f);
                float v3 = fmaxf(hm[g * 4 + 3], 0.f);
                uint2 pk = make_uint2(pk2bf(v0, v1), pk2bf(v2, v3));
                int gran = (pt * 4 + g) ^ hsw;
                *(uint2*)&hmidT[hrow * 64 + gran * 8 + half * 4] = pk;
            }
        }
        #pragma unroll
        for (int s = 0; s < 2; ++s) {
            bf16x8 acw = *(const bf16x8*)(cwrow + p0 + s * 32 + quad * 8);
            #pragma unroll
            for (int hj = 0; hj < 2; ++hj) {
                int hr = wv * 32 + hj * 16 + l15;
                int gr = (s * 4 + quad) ^ (hr & 7);
                bf16x8 bh = *(const bf16x8*)&hmidT[hr * 64 + gr * 8];
                acc[hj] = __builtin_amdgcn_mfma_f32_16x16x32_bf16(acw, bh, acc[hj], 0, 0, 0);
            }
        }
    }
    #pragma unroll
    for (int hj = 0; hj < 2; ++hj) {
        int h = h0 + wv * 32 + hj * 16 + l15;
        if (h < HPAD) {
            #pragma unroll
            for (int r = 0; r < 4; ++r) {
                int m = quad * 4 + r;
                Gb[(size_t)(b * 16 + m) * NHPCOL + n * HPAD + h] = f2bf(acc[hj][r]);
            }
        }
    }
}

// ---------------------------------------------------------------------------
// MFMA split-K GEMM: Y[256][512] += Gb[.., n-slice] * W2T[d][n-slice]^T
// grid (ct=4, rt=4, n=16)
// ---------------------------------------------------------------------------
__global__ __launch_bounds__(256) void k_ygemm(
    const u16* __restrict__ G, const u16* __restrict__ W2T, float* __restrict__ Y) {
    __shared__ u16 AsL[64 * 40];
    __shared__ u16 BsL[128 * 40];
    const int ct = blockIdx.x, rt = blockIdx.y, n = blockIdx.z;
    const int tid = threadIdx.x;
    const int wv = tid >> 6, lane = tid & 63, quad = lane >> 4, l15 = lane & 15;
    const int m0 = rt * 64, d0 = ct * 128;
    f32x4 acc[4][2] = {};
    for (int kb = 0; kb < HPAD; kb += 32) {
        {
            int am = tid >> 2, akg = (tid & 3) * 8;
            *(uint4*)&AsL[am * 40 + akg] =
                *(const uint4*)(G + (size_t)(m0 + am) * NHPCOL + n * HPAD + kb + akg);
            int bc = tid >> 1, bkg = (tid & 1) * 16;
            const u16* t = W2T + (size_t)(d0 + bc) * NHPCOL + n * HPAD + kb + bkg;
            *(uint4*)&BsL[bc * 40 + bkg]     = *(const uint4*)t;
            *(uint4*)&BsL[bc * 40 + bkg + 8] = *(const uint4*)(t + 8);
        }
        __syncthreads();
        bf16x8 af[4], bfr[2];
        #pragma unroll
        for (int i = 0; i < 4; ++i) af[i] = *(const bf16x8*)&AsL[(i * 16 + l15) * 40 + quad * 8];
        #pragma unroll
        for (int j = 0; j < 2; ++j) bfr[j] = *(const bf16x8*)&BsL[(wv * 32 + j * 16 + l15) * 40 + quad * 8];
        #pragma unroll
        for (int i = 0; i < 4; ++i)
            #pragma unroll
            for (int j = 0; j < 2; ++j)
                acc[i][j] = __builtin_amdgcn_mfma_f32_16x16x32_bf16(af[i], bfr[j], acc[i][j], 0, 0, 0);
        __syncthreads();
    }
    #pragma unroll
    for (int i = 0; i < 4; ++i)
        #pragma unroll
        for (int j = 0; j < 2; ++j) {
            int d = d0 + wv * 32 + j * 16 + l15;
            int r0 = m0 + i * 16 + quad * 4;
            #pragma unroll
            for (int r = 0; r < 4; ++r)
                atomicAdd(&Y[(size_t)(r0 + r) * 512 + d], acc[i][j][r]);
        }
}

// ---------------------------------------------------------------------------
// MFMA split-K GEMM: out[16][512] += Yflat[16][k-slice] * WoutT[o][k-slice]^T
// grid (ct=4, ks=16)
// ---------------------------------------------------------------------------
__global__ __launch_bounds__(256) void k_outgemm(
    const float* __restrict__ Y, const u16* __restrict__ WoutT, float* __restrict__ out) {
    __shared__ u16 AsL[16 * 40];
    __shared__ u16 BsL[128 * 40];
    const int ct = blockIdx.x, ks = blockIdx.y;
    const int tid = threadIdx.x;
    const int wv = tid >> 6, lane = tid & 63, quad = lane >> 4, l15 = lane & 15;
    const int o0 = ct * 128, kbase = ks * 512;
    f32x4 acc[2] = {};
    for (int kb = 0; kb < 512; kb += 32) {
        {
            int r = tid >> 4, k2 = (tid & 15) * 2;
            float2 v = *(const float2*)&Y[(size_t)r * 8192 + kbase + kb + k2];
            AsL[r * 40 + k2]     = f2bf(v.x);
            AsL[r * 40 + k2 + 1] = f2bf(v.y);
            int bc = tid >> 1, bkg = (tid & 1) * 16;
            const u16* t = WoutT + (size_t)(o0 + bc) * 8192 + kbase + kb + bkg;
            *(uint4*)&BsL[bc * 40 + bkg]     = *(const uint4*)t;
            *(uint4*)&BsL[bc * 40 + bkg + 8] = *(const uint4*)(t + 8);
        }
        __syncthreads();
        bf16x8 af = *(const bf16x8*)&AsL[l15 * 40 + quad * 8];
        #pragma unroll
        for (int j = 0; j < 2; ++j) {
            bf16x8 bfr = *(const bf16x8*)&BsL[(wv * 32 + j * 16 + l15) * 40 + quad * 8];
            acc[j] = __builtin_amdgcn_mfma_f32_16x16x32_bf16(af, bfr, acc[j], 0, 0, 0);
        }
        __syncthreads();
    }
    #pragma unroll
    for (int j = 0; j < 2; ++j) {
        int o = o0 + wv * 32 + j * 16 + l15;
        #pragma unroll
        for (int r = 0; r < 4; ++r)
            atomicAdd(&out[(size_t)(quad * 4 + r) * 512 + o], acc[j][r]);
    }
}

// ---------------------------------------------------------------------------
extern "C" void kernel_launch(void* const* d_in, const int* in_sizes, int n_in,
                              void* d_out, int out_size, void* d_ws, size_t ws_size,
                              hipStream_t stream) {
    const float* x    = (const float*)d_in[0];
    const float* phi  = (const float*)d_in[1];
    const float* W1   = (const float*)d_in[2];
    const float* b1   = (const float*)d_in[3];
    const float* W2   = (const float*)d_in[4];
    const float* b2   = (const float*)d_in[5];
    const float* Wout = (const float*)d_in[6];
    const float* bout = (const float*)d_in[7];
    float* out = (float*)d_out;

    // Workspace (peak 66,748,416 B). ph/pl die after lgemm; DwT/CwB/T1b/Gb
    // alias their region (written strictly after lgemm completes).
    char* base = (char*)d_ws;
    float* logits = (float*)(base + 0);           // 11,173,888
    u16*   ph     = (u16*)(base + 11173888);      // 11,206,656 -> 22,380,544
    u16*   pl     = (u16*)(base + 22380544);      // 11,206,656 -> 33,587,200
    u16*   DwT    = (u16*)(base + 11173888);      //  5,767,168 (alias, post-lgemm)
    u16*   CwB    = (u16*)(base + 16941056);      //  5,767,168 (alias)
    u16*   T1b    = (u16*)(base + 22708224);      //  5,767,168 (alias)
    u16*   Gb     = (u16*)(base + 28475392);      //  5,767,168 (alias, ends 34,242,560)
    u16*   W1T    = (u16*)(base + 34242560);      // 11,534,336 -> 45,776,896
    u16*   xh     = (u16*)(base + 45776896);      //    262,144 -> 46,039,040
    u16*   xl     = (u16*)(base + 46039040);      //    262,144 -> 46,301,184
    u16*   W2T    = (u16*)(base + 46301184);      // 11,534,336 -> 57,835,520
    u16*   WoutT  = (u16*)(base + 57835520);      //  8,388,608 -> 66,224,128
    float* Y      = (float*)(base + 66224128);    //    524,288 -> 66,748,416

    k_prep    <<<dim3(5880), 256, 0, stream>>>(x, phi, W1, W2, Wout, b2, bout,
                                               ph, pl, W1T, W2T, WoutT, xh, xl, Y, out);
    k_lgemm   <<<dim3(171, 4), 256, 0, stream>>>(xh, xl, ph, pl, logits);
    k_softmax <<<dim3(960), 256, 0, stream>>>(logits, DwT, CwB);
    k_t1gemm  <<<dim3(88, 2), 256, 0, stream>>>(xh, W1T, T1b);
    k_mid     <<<dim3(6, 16, 16), 256, 0, stream>>>(T1b, DwT, CwB, b1, Gb);
    k_ygemm   <<<dim3(4, 4, 16), 256, 0, stream>>>(Gb, W2T, Y);
    k_outgemm <<<dim3(4, 16), 256, 0, stream>>>(Y, WoutT, out);
}

// Round 10
// 262.508 us; speedup vs baseline: 1.2144x; 1.0368x over previous
//
#include <hip/hip_runtime.h>
#include <hip/hip_bf16.h>
#include <math.h>

typedef unsigned int   u32;
typedef unsigned short u16;
typedef __bf16 bf16;
typedef bf16  bf16x8  __attribute__((ext_vector_type(8)));
typedef float f32x4   __attribute__((ext_vector_type(4)));
typedef float f32x16  __attribute__((ext_vector_type(16)));

#define BBATCH 16
#define MTOK   16
#define NEXP   16
#define DDIM   512
#define HDIM   682
#define HPAD   704            // 11*64
#define NHCOL  (NEXP*HDIM)    // 10912
#define NHPCOL (NEXP*HPAD)    // 11264
#define BM     (BBATCH*MTOK)  // 256

__device__ __forceinline__ u16 f2bf(float f) {
    u32 u = __builtin_bit_cast(u32, f);
    u += 0x7fffu + ((u >> 16) & 1u);
    return (u16)(u >> 16);
}
__device__ __forceinline__ float bf2f(u16 h) {
    u32 u = ((u32)h) << 16;
    return __builtin_bit_cast(float, u);
}
__device__ __forceinline__ u32 pk2bf(float a, float b) {
    __hip_bfloat162 t = __float22bfloat162_rn(float2{a, b});
    u32 r;
    __builtin_memcpy(&r, &t, 4);
    return r;
}

// ---------------------------------------------------------------------------
// k_prep: x -> xh/xl bf16 planes; Y = sum_n b2; out = bout.  grid 672
// ---------------------------------------------------------------------------
__global__ __launch_bounds__(256) void k_prep(
    const float* __restrict__ x, const float* __restrict__ b2,
    const float* __restrict__ bout,
    u16* __restrict__ xh, u16* __restrict__ xl,
    float* __restrict__ Y, float* __restrict__ out) {
    const int bid = blockIdx.x, tid = threadIdx.x;
    if (bid < 128) {
        int i = (bid * 256 + tid) * 4;
        float4 v = *(const float4*)&x[i];
        float a[4] = {v.x, v.y, v.z, v.w};
        u16 hh[4], ll[4];
        #pragma unroll
        for (int j = 0; j < 4; ++j) {
            hh[j] = f2bf(a[j]);
            ll[j] = f2bf(a[j] - bf2f(hh[j]));
        }
        *(uint2*)&xh[i] = make_uint2((u32)hh[0] | ((u32)hh[1] << 16), (u32)hh[2] | ((u32)hh[3] << 16));
        *(uint2*)&xl[i] = make_uint2((u32)ll[0] | ((u32)ll[1] << 16), (u32)ll[2] | ((u32)ll[3] << 16));
    } else if (bid < 640) {
        int idx = (bid - 128) * 256 + tid;
        int d = idx & 511;
        float s = 0.f;
        #pragma unroll
        for (int nn = 0; nn < 16; ++nn) s += b2[nn * 512 + d];
        Y[idx] = s;
    } else {
        int idx = (bid - 640) * 256 + tid;
        out[idx] = bout[idx & 511];
    }
}

// ---------------------------------------------------------------------------
// Split-bf16 MFMA GEMM with in-kernel phi transpose+split:
// logits[256][10912] fp32 = (xh+xl)[256][512] * phi^T (3-product)
// grid (ct=171, rt=4); 64x64 tile
// ---------------------------------------------------------------------------
__global__ __launch_bounds__(256) void k_lgemm(
    const u16* __restrict__ xh, const u16* __restrict__ xl,
    const float* __restrict__ phi, float* __restrict__ C) {
    __shared__ u16 AH[64 * 40], AL[64 * 40], BH[64 * 40], BL[64 * 40];
    __shared__ float F[32 * 68];          // [k=32][64 cols] fp32 staging
    const int ct = blockIdx.x, rt = blockIdx.y;
    const int tid = threadIdx.x;
    const int wv = tid >> 6, lane = tid & 63, quad = lane >> 4, l15 = lane & 15;
    f32x4 acc[4] = {};
    for (int kb = 0; kb < 512; kb += 32) {
        { // A staging from xh/xl
            int r = tid >> 2, kg = (tid & 3) * 8;
            size_t ao = (size_t)(rt * 64 + r) * 512 + kb + kg;
            *(uint4*)&AH[r * 40 + kg] = *(const uint4*)(xh + ao);
            *(uint4*)&AL[r * 40 + kg] = *(const uint4*)(xl + ao);
        }
        { // B step1: phi[kb+dl][c0..c0+8) -> F
            int dl = tid >> 3, cg = (tid & 7) * 8;
            int c0 = ct * 64 + cg;
            const float* src = phi + (size_t)(kb + dl) * NHCOL + c0;
            float v[8];
            if (c0 + 8 <= NHCOL) {
                *(float4*)&v[0] = *(const float4*)&src[0];
                *(float4*)&v[4] = *(const float4*)&src[4];
            } else {
                #pragma unroll
                for (int i = 0; i < 8; ++i) v[i] = (c0 + i < NHCOL) ? src[i] : 0.f;
            }
            #pragma unroll
            for (int i = 0; i < 8; ++i) F[dl * 68 + cg + i] = v[i];
        }
        __syncthreads();
        { // B step2: transpose + hi/lo split -> BH/BL[c][k]
            int cc = tid & 63, q = tid >> 6;
            u16 th[8], tl[8];
            #pragma unroll
            for (int i = 0; i < 8; ++i) {
                float v = F[(q * 8 + i) * 68 + cc];
                th[i] = f2bf(v);
                tl[i] = f2bf(v - bf2f(th[i]));
            }
            *(uint4*)&BH[cc * 40 + q * 8] = *(uint4*)&th[0];
            *(uint4*)&BL[cc * 40 + q * 8] = *(uint4*)&tl[0];
        }
        __syncthreads();
        bf16x8 ah = *(const bf16x8*)&AH[(wv * 16 + l15) * 40 + quad * 8];
        bf16x8 al = *(const bf16x8*)&AL[(wv * 16 + l15) * 40 + quad * 8];
        #pragma unroll
        for (int j = 0; j < 4; ++j) {
            bf16x8 bh = *(const bf16x8*)&BH[(j * 16 + l15) * 40 + quad * 8];
            bf16x8 bl = *(const bf16x8*)&BL[(j * 16 + l15) * 40 + quad * 8];
            acc[j] = __builtin_amdgcn_mfma_f32_16x16x32_bf16(ah, bh, acc[j], 0, 0, 0);
            acc[j] = __builtin_amdgcn_mfma_f32_16x16x32_bf16(ah, bl, acc[j], 0, 0, 0);
            acc[j] = __builtin_amdgcn_mfma_f32_16x16x32_bf16(al, bh, acc[j], 0, 0, 0);
        }
        __syncthreads();
    }
    #pragma unroll
    for (int j = 0; j < 4; ++j) {
        int col = ct * 64 + j * 16 + l15;
        if (col < NHCOL) {
            int r0 = rt * 64 + wv * 16 + quad * 4;
            #pragma unroll
            for (int r = 0; r < 4; ++r)
                C[(size_t)(r0 + r) * NHCOL + col] = acc[j][r];
        }
    }
}

// ---------------------------------------------------------------------------
// k_softmax (960 blocks):
//  [0,704)   Dw: softmax over m -> DwT[b][n][p pad704][16 m] bf16
//  [704,960) Cw: softmax_p(softmax_n) -> CwB[b][n][m][704 p] bf16
// ---------------------------------------------------------------------------
__global__ __launch_bounds__(256) void k_softmax(
    const float* __restrict__ L, u16* __restrict__ DwT, u16* __restrict__ CwB) {
    __shared__ float row[NHCOL];
    const int bid = blockIdx.x, tid = threadIdx.x;
    if (bid < 704) {
        const int b = bid / 44;
        const int c = (bid % 44) * 256 + tid;          // n*704+p
        const int n = c / HPAD, p = c - n * HPAD;
        u16 o[16];
        if (p < HDIM) {
            float v[16];
            float mx = -1e30f;
            #pragma unroll
            for (int m = 0; m < 16; ++m) {
                v[m] = L[(b * 16 + m) * NHCOL + n * HDIM + p];
                mx = fmaxf(mx, v[m]);
            }
            float s = 0.f;
            #pragma unroll
            for (int m = 0; m < 16; ++m) { v[m] = expf(v[m] - mx); s += v[m]; }
            float inv = 1.f / s;
            #pragma unroll
            for (int m = 0; m < 16; ++m) o[m] = f2bf(v[m] * inv);
        } else {
            #pragma unroll
            for (int m = 0; m < 16; ++m) o[m] = 0;
        }
        u16* dst = DwT + (size_t)((b * 16 + n) * HPAD + p) * 16;
        *(uint4*)dst = *(uint4*)&o[0];
        *(uint4*)(dst + 8) = *(uint4*)&o[8];
    } else {
        const int j = bid - 704;
        const int m = j & 15, b = j >> 4;
        const float* Lrow = L + (size_t)(b * 16 + m) * NHCOL;
        for (int i = tid; i < NHCOL; i += 256) row[i] = Lrow[i];
        __syncthreads();
        for (int p = tid; p < HDIM; p += 256) {
            float v[16];
            float mx = -1e30f;
            #pragma unroll
            for (int n = 0; n < 16; ++n) { v[n] = row[n * HDIM + p]; mx = fmaxf(mx, v[n]); }
            float s = 0.f;
            #pragma unroll
            for (int n = 0; n < 16; ++n) { v[n] = expf(v[n] - mx); s += v[n]; }
            float inv = 1.f / s;
            #pragma unroll
            for (int n = 0; n < 16; ++n) row[n * HDIM + p] = expf(v[n] * inv);  // cache exp(s1)
        }
        __syncthreads();
        const int wv = tid >> 6, lane = tid & 63;
        for (int nn = 0; nn < 4; ++nn) {
            int n = wv * 4 + nn;
            float s = 0.f;
            for (int p = lane; p < HDIM; p += 64) s += row[n * HDIM + p];
            #pragma unroll
            for (int off = 32; off > 0; off >>= 1) s += __shfl_xor(s, off);
            float inv = 1.f / s;
            u16* dst = CwB + (size_t)(((b * 16 + n) * 16 + m)) * HPAD;
            for (int p = lane; p < HDIM; p += 64) dst[p] = f2bf(row[n * HDIM + p] * inv);
            if (lane < HPAD - HDIM) dst[HDIM + lane] = 0;
        }
    }
}

// ---------------------------------------------------------------------------
// MFMA GEMM with in-kernel W1 transpose:
// T1b[256][11264] bf16 = xh[256][512] * W1view^T, col = n*704+h
// grid (ct=176, rt=2); 128 rows x 64 cols per block (tiles never straddle n)
// ---------------------------------------------------------------------------
__global__ __launch_bounds__(256) void k_t1gemm(
    const u16* __restrict__ A, const float* __restrict__ W1, u16* __restrict__ C) {
    __shared__ u16 As[128 * 40];
    __shared__ u16 Bs[64 * 40];
    __shared__ float F[32 * 68];
    const int ct = blockIdx.x, rt = blockIdx.y;
    const int tid = threadIdx.x;
    const int wv = tid >> 6, lane = tid & 63, quad = lane >> 4, l15 = lane & 15;
    const int rh = wv & 1, ch = wv >> 1;             // wave: 64 rows x 32 cols
    const int n = ct / 11, h0 = (ct % 11) * 64;
    f32x4 acc[4][2] = {};
    for (int kb = 0; kb < 512; kb += 32) {
        { // A staging
            int r = tid >> 1, kg = (tid & 1) * 16;
            const u16* s = A + (size_t)(rt * 128 + r) * 512 + kb + kg;
            *(uint4*)&As[r * 40 + kg]     = *(const uint4*)s;
            *(uint4*)&As[r * 40 + kg + 8] = *(const uint4*)(s + 8);
        }
        { // B step1: W1[n][kb+dl][h0+cg..+8) -> F (float2 path, 8B-aligned)
            int dl = tid >> 3, cg = (tid & 7) * 8;
            int h = h0 + cg;
            const float* wr = W1 + ((size_t)n * 512 + kb + dl) * HDIM + h;
            float v[8];
            if (h + 8 <= HDIM) {
                #pragma unroll
                for (int i = 0; i < 4; ++i) {
                    float2 t = *(const float2*)&wr[i * 2];
                    v[i * 2] = t.x; v[i * 2 + 1] = t.y;
                }
            } else {
                #pragma unroll
                for (int i = 0; i < 8; ++i) v[i] = (h + i < HDIM) ? wr[i] : 0.f;
            }
            #pragma unroll
            for (int i = 0; i < 8; ++i) F[dl * 68 + cg + i] = v[i];
        }
        __syncthreads();
        { // B step2: transpose + cvt -> Bs[c][k]
            int cc = tid & 63, q = tid >> 6;
            u16 tv[8];
            #pragma unroll
            for (int i = 0; i < 8; ++i) tv[i] = f2bf(F[(q * 8 + i) * 68 + cc]);
            *(uint4*)&Bs[cc * 40 + q * 8] = *(uint4*)&tv[0];
        }
        __syncthreads();
        bf16x8 af[4], bfr[2];
        #pragma unroll
        for (int i = 0; i < 4; ++i)
            af[i] = *(const bf16x8*)&As[(rh * 64 + i * 16 + l15) * 40 + quad * 8];
        #pragma unroll
        for (int j = 0; j < 2; ++j)
            bfr[j] = *(const bf16x8*)&Bs[(ch * 32 + j * 16 + l15) * 40 + quad * 8];
        #pragma unroll
        for (int i = 0; i < 4; ++i)
            #pragma unroll
            for (int j = 0; j < 2; ++j)
                acc[i][j] = __builtin_amdgcn_mfma_f32_16x16x32_bf16(af[i], bfr[j], acc[i][j], 0, 0, 0);
        __syncthreads();
    }
    #pragma unroll
    for (int i = 0; i < 4; ++i)
        #pragma unroll
        for (int j = 0; j < 2; ++j) {
            int col = ct * 64 + ch * 32 + j * 16 + l15;
            int r0  = rt * 128 + rh * 64 + i * 16 + quad * 4;
            #pragma unroll
            for (int r = 0; r < 4; ++r)
                C[(size_t)(r0 + r) * NHPCOL + col] = f2bf(acc[i][j][r]);
        }
}

// ---------------------------------------------------------------------------
// Fused middle:
//  stage1: hmid = relu(b1 + Dw^T·T1) via 32x32x16; stage2: G += Cw·hmid
// grid (6, 16, 16)
// ---------------------------------------------------------------------------
__global__ __launch_bounds__(256) void k_mid(
    const u16* __restrict__ T1b, const u16* __restrict__ DwT,
    const u16* __restrict__ CwB, const float* __restrict__ b1,
    u16* __restrict__ Gb) {
    __shared__ u16 T1T[128 * 24];
    __shared__ u16 hmidT[128 * 64];
    const int ht = blockIdx.x, n = blockIdx.y, b = blockIdx.z;
    const int tid = threadIdx.x;
    const int wv = tid >> 6, lane = tid & 63;
    const int quad = lane >> 4, l15 = lane & 15;
    const int l31 = lane & 31, half = lane >> 5;
    const int h0 = ht * 128;
    const int b16n = b * 16 + n;

    {
        int m = tid & 15, hh0 = (tid >> 4) * 8;
        u16 v[8];
        if (h0 + hh0 + 8 <= HPAD) {
            *(uint4*)v = *(const uint4*)(T1b + (size_t)(b * 16 + m) * NHPCOL + n * HPAD + h0 + hh0);
        } else {
            #pragma unroll
            for (int i = 0; i < 8; ++i) v[i] = 0;
        }
        #pragma unroll
        for (int i = 0; i < 8; ++i) T1T[(hh0 + i) * 24 + m] = v[i];
    }
    __syncthreads();

    const int hrow = wv * 32 + l31;
    bf16x8 bt1 = *(const bf16x8*)&T1T[hrow * 24 + half * 8];
    int hg1 = h0 + hrow;
    float biasf = (hg1 < HDIM) ? b1[n * HDIM + hg1] : 0.f;
    f32x16 cbias;
    #pragma unroll
    for (int i = 0; i < 16; ++i) cbias[i] = biasf;

    const u16* dwbase = DwT + (size_t)(b16n * HPAD) * 16;
    const u16* cwrow  = CwB + (size_t)(b16n * 16 + l15) * HPAD;

    f32x4 acc[2] = {};
    const int hsw = hrow & 7;
    for (int c = 0; c < 11; ++c) {
        const int p0 = c * 64;
        #pragma unroll
        for (int pt = 0; pt < 2; ++pt) {
            bf16x8 adw = *(const bf16x8*)(dwbase + (size_t)(p0 + pt * 32 + l31) * 16 + half * 8);
            f32x16 hm = __builtin_amdgcn_mfma_f32_32x32x16_bf16(adw, bt1, cbias, 0, 0, 0);
            #pragma unroll
            for (int g = 0; g < 4; ++g) {
                float v0 = fmaxf(hm[g * 4 + 0], 0.f);
                float v1 = fmaxf(hm[g * 4 + 1], 0.f);
                float v2 = fmaxf(hm[g * 4 + 2], 0.f);
                float v3 = fmaxf(hm[g * 4 + 3], 0.f);
                uint2 pk = make_uint2(pk2bf(v0, v1), pk2bf(v2, v3));
                int gran = (pt * 4 + g) ^ hsw;
                *(uint2*)&hmidT[hrow * 64 + gran * 8 + half * 4] = pk;
            }
        }
        #pragma unroll
        for (int s = 0; s < 2; ++s) {
            bf16x8 acw = *(const bf16x8*)(cwrow + p0 + s * 32 + quad * 8);
            #pragma unroll
            for (int hj = 0; hj < 2; ++hj) {
                int hr = wv * 32 + hj * 16 + l15;
                int gr = (s * 4 + quad) ^ (hr & 7);
                bf16x8 bh = *(const bf16x8*)&hmidT[hr * 64 + gr * 8];
                acc[hj] = __builtin_amdgcn_mfma_f32_16x16x32_bf16(acw, bh, acc[hj], 0, 0, 0);
            }
        }
    }
    #pragma unroll
    for (int hj = 0; hj < 2; ++hj) {
        int h = h0 + wv * 32 + hj * 16 + l15;
        if (h < HPAD) {
            #pragma unroll
            for (int r = 0; r < 4; ++r) {
                int m = quad * 4 + r;
                Gb[(size_t)(b * 16 + m) * NHPCOL + n * HPAD + h] = f2bf(acc[hj][r]);
            }
        }
    }
}

// ---------------------------------------------------------------------------
// MFMA split-K GEMM with in-kernel W2 transpose:
// Y[256][512] += Gb[.., n-slice] * W2[n]^T.  grid (ct=4, rt=4, n=16)
// ---------------------------------------------------------------------------
__global__ __launch_bounds__(256) void k_ygemm(
    const u16* __restrict__ G, const float* __restrict__ W2, float* __restrict__ Y) {
    __shared__ u16 AsL[64 * 40];
    __shared__ u16 BsL[128 * 40];
    __shared__ float F[32 * 132];
    const int ct = blockIdx.x, rt = blockIdx.y, n = blockIdx.z;
    const int tid = threadIdx.x;
    const int wv = tid >> 6, lane = tid & 63, quad = lane >> 4, l15 = lane & 15;
    const int m0 = rt * 64, d0 = ct * 128;
    f32x4 acc[4][2] = {};
    for (int kb = 0; kb < HPAD; kb += 32) {
        { // A staging from Gb
            int am = tid >> 2, akg = (tid & 3) * 8;
            *(uint4*)&AsL[am * 40 + akg] =
                *(const uint4*)(G + (size_t)(m0 + am) * NHPCOL + n * HPAD + kb + akg);
        }
        { // B step1: W2[n][kb+hl][d0+cg..+16) -> F
            int hl = tid >> 3, cg = (tid & 7) * 16;
            int h = kb + hl;
            float v[16];
            if (h < HDIM) {
                const float* src = W2 + ((size_t)n * HDIM + h) * 512 + d0 + cg;
                *(float4*)&v[0]  = *(const float4*)&src[0];
                *(float4*)&v[4]  = *(const float4*)&src[4];
                *(float4*)&v[8]  = *(const float4*)&src[8];
                *(float4*)&v[12] = *(const float4*)&src[12];
            } else {
                #pragma unroll
                for (int i = 0; i < 16; ++i) v[i] = 0.f;
            }
            #pragma unroll
            for (int i = 0; i < 16; ++i) F[hl * 132 + cg + i] = v[i];
        }
        __syncthreads();
        { // B step2: transpose + cvt -> BsL[d][k]
            int cc = tid & 127, half = tid >> 7;
            u16 tv[16];
            #pragma unroll
            for (int i = 0; i < 16; ++i) tv[i] = f2bf(F[(half * 16 + i) * 132 + cc]);
            *(uint4*)&BsL[cc * 40 + half * 16]     = *(uint4*)&tv[0];
            *(uint4*)&BsL[cc * 40 + half * 16 + 8] = *(uint4*)&tv[8];
        }
        __syncthreads();
        bf16x8 af[4], bfr[2];
        #pragma unroll
        for (int i = 0; i < 4; ++i) af[i] = *(const bf16x8*)&AsL[(i * 16 + l15) * 40 + quad * 8];
        #pragma unroll
        for (int j = 0; j < 2; ++j) bfr[j] = *(const bf16x8*)&BsL[(wv * 32 + j * 16 + l15) * 40 + quad * 8];
        #pragma unroll
        for (int i = 0; i < 4; ++i)
            #pragma unroll
            for (int j = 0; j < 2; ++j)
                acc[i][j] = __builtin_amdgcn_mfma_f32_16x16x32_bf16(af[i], bfr[j], acc[i][j], 0, 0, 0);
        __syncthreads();
    }
    #pragma unroll
    for (int i = 0; i < 4; ++i)
        #pragma unroll
        for (int j = 0; j < 2; ++j) {
            int d = d0 + wv * 32 + j * 16 + l15;
            int r0 = m0 + i * 16 + quad * 4;
            #pragma unroll
            for (int r = 0; r < 4; ++r)
                atomicAdd(&Y[(size_t)(r0 + r) * 512 + d], acc[i][j][r]);
        }
}

// ---------------------------------------------------------------------------
// MFMA split-K GEMM with in-kernel Wout transpose:
// out[16][512] += Yflat[16][k-slice] * Wout[k-slice]^T.  grid (ct=4, ks=16)
// ---------------------------------------------------------------------------
__global__ __launch_bounds__(256) void k_outgemm(
    const float* __restrict__ Y, const float* __restrict__ Wout, float* __restrict__ out) {
    __shared__ u16 AsL[16 * 40];
    __shared__ u16 BsL[128 * 40];
    __shared__ float F[32 * 132];
    const int ct = blockIdx.x, ks = blockIdx.y;
    const int tid = threadIdx.x;
    const int wv = tid >> 6, lane = tid & 63, quad = lane >> 4, l15 = lane & 15;
    const int o0 = ct * 128, kbase = ks * 512;
    f32x4 acc[2] = {};
    for (int kb = 0; kb < 512; kb += 32) {
        { // A staging from Y fp32
            int r = tid >> 4, k2 = (tid & 15) * 2;
            float2 v = *(const float2*)&Y[(size_t)r * 8192 + kbase + kb + k2];
            AsL[r * 40 + k2]     = f2bf(v.x);
            AsL[r * 40 + k2 + 1] = f2bf(v.y);
        }
        { // B step1: Wout[kbase+kb+kl][o0+cg..+16) -> F
            int kl = tid >> 3, cg = (tid & 7) * 16;
            const float* src = Wout + (size_t)(kbase + kb + kl) * 512 + o0 + cg;
            float v[16];
            *(float4*)&v[0]  = *(const float4*)&src[0];
            *(float4*)&v[4]  = *(const float4*)&src[4];
            *(float4*)&v[8]  = *(const float4*)&src[8];
            *(float4*)&v[12] = *(const float4*)&src[12];
            #pragma unroll
            for (int i = 0; i < 16; ++i) F[kl * 132 + cg + i] = v[i];
        }
        __syncthreads();
        { // B step2: transpose + cvt
            int cc = tid & 127, half = tid >> 7;
            u16 tv[16];
            #pragma unroll
            for (int i = 0; i < 16; ++i) tv[i] = f2bf(F[(half * 16 + i) * 132 + cc]);
            *(uint4*)&BsL[cc * 40 + half * 16]     = *(uint4*)&tv[0];
            *(uint4*)&BsL[cc * 40 + half * 16 + 8] = *(uint4*)&tv[8];
        }
        __syncthreads();
        bf16x8 af = *(const bf16x8*)&AsL[l15 * 40 + quad * 8];
        #pragma unroll
        for (int j = 0; j < 2; ++j) {
            bf16x8 bfr = *(const bf16x8*)&BsL[(wv * 32 + j * 16 + l15) * 40 + quad * 8];
            acc[j] = __builtin_amdgcn_mfma_f32_16x16x32_bf16(af, bfr, acc[j], 0, 0, 0);
        }
        __syncthreads();
    }
    #pragma unroll
    for (int j = 0; j < 2; ++j) {
        int o = o0 + wv * 32 + j * 16 + l15;
        #pragma unroll
        for (int r = 0; r < 4; ++r)
            atomicAdd(&out[(size_t)(quad * 4 + r) * 512 + o], acc[j][r]);
    }
}

// ---------------------------------------------------------------------------
extern "C" void kernel_launch(void* const* d_in, const int* in_sizes, int n_in,
                              void* d_out, int out_size, void* d_ws, size_t ws_size,
                              hipStream_t stream) {
    const float* x    = (const float*)d_in[0];
    const float* phi  = (const float*)d_in[1];
    const float* W1   = (const float*)d_in[2];
    const float* b1   = (const float*)d_in[3];
    const float* W2   = (const float*)d_in[4];
    const float* b2   = (const float*)d_in[5];
    const float* Wout = (const float*)d_in[6];
    const float* bout = (const float*)d_in[7];
    float* out = (float*)d_out;

    // Workspace (peak ~35.3 MB; no transposed weight copies anymore)
    char* base = (char*)d_ws;
    float* logits = (float*)(base + 0);           // 11,173,888
    u16*   DwT    = (u16*)(base + 11173888);      //  5,767,168 -> 16,941,056
    u16*   CwB    = (u16*)(base + 16941056);      //  5,767,168 -> 22,708,224
    u16*   T1b    = (u16*)(base + 22708224);      //  5,767,168 -> 28,475,392
    u16*   Gb     = (u16*)(base + 28475392);      //  5,767,168 -> 34,242,560
    u16*   xh     = (u16*)(base + 34242560);      //    262,144 -> 34,504,704
    u16*   xl     = (u16*)(base + 34504704);      //    262,144 -> 34,766,848
    float* Y      = (float*)(base + 34766848);    //    524,288 -> 35,291,136

    k_prep    <<<dim3(672), 256, 0, stream>>>(x, b2, bout, xh, xl, Y, out);
    k_lgemm   <<<dim3(171, 4), 256, 0, stream>>>(xh, xl, phi, logits);
    k_softmax <<<dim3(960), 256, 0, stream>>>(logits, DwT, CwB);
    k_t1gemm  <<<dim3(176, 2), 256, 0, stream>>>(xh, W1, T1b);
    k_mid     <<<dim3(6, 16, 16), 256, 0, stream>>>(T1b, DwT, CwB, b1, Gb);
    k_ygemm   <<<dim3(4, 4, 16), 256, 0, stream>>>(Gb, W2, Y);
    k_outgemm <<<dim3(4, 16), 256, 0, stream>>>(Y, Wout, out);
}